// Round 6
// baseline (280.617 us; speedup 1.0000x reference)
//
#include <hip/hip_runtime.h>

// TTLinearR: y = x @ W^T + b, W (4096x4096) = TT ranks [1,64,64,64,64,64,1].
// W = Amat(4096,64) @ Bmat(64,4096):
//   Amat = ((c0r(16,64)@c1r(64,1024)).reshape(256,64)@c2r(64,1024)).reshape(4096,64)
//   S3(1024,16) = c4r(1024,64)@c5r(64,16); Bmat(64,4096) = (c3r(1024,64)@S3view(64,256)) flat
// y = (x @ Bmat^T) @ Amat^T + b.  Traffic floor ~258 MB (~41 us).
//
// R9: gemm1 stuck at ~70 us (inferred, F-cancelling delta accounting) in both
// streaming variants: R5's ping-pong prefetched a buffer right after consuming
// it -> only HALF an iteration (~120 cyc) of latency cover vs ~900-cyc HBM.
// Fix: depth-4 x-prefetch ring (consume step s -> issue s+4 into same slot),
// depth-2 for L2-resident B. Hand-unrolled 4-step body, static reg indexing,
// ~105 VGPR under the 128 cap. gemm2_y (write-floor) and chains unchanged.

#define TOK 8192
#define DIN 4096
#define DOUT 4096
#define RNK 64

// ---- gemm2 geometry (R3 gemm2_y, at write floor) ----
#define G2M 128          // tokens per block
#define G2N 256          // out-cols per block
#define AS 72            // LDS row stride in shorts (64 + 8 pad)

typedef __bf16 bf16x8 __attribute__((ext_vector_type(8)));
typedef float f32x4 __attribute__((ext_vector_type(4)));
typedef float f32x16 __attribute__((ext_vector_type(16)));

__device__ __forceinline__ unsigned short f2bf(float f) {
  unsigned int u = __float_as_uint(f);
  u += 0x7FFFu + ((u >> 16) & 1u);  // RNE
  return (unsigned short)(u >> 16);
}

// ---- chain1: S1(16x1024) = c0(16,64)@c1(64,1024); S3(1024x16) = c4(1024,64)@c5(64,16)
__global__ void chain1(const float* __restrict__ c0, const float* __restrict__ c1,
                       const float* __restrict__ c4, const float* __restrict__ c5,
                       float* __restrict__ S1, float* __restrict__ S3) {
  int b = blockIdx.x;
  if (b < 64) {
    int idx = b * 256 + threadIdx.x;
    int m = idx >> 10, n = idx & 1023;
    const float* a = c0 + m * 64;
    float acc = 0.f;
#pragma unroll
    for (int k = 0; k < 64; ++k) acc += a[k] * c1[k * 1024 + n];
    S1[idx] = acc;
  } else {
    int idx = (b - 64) * 256 + threadIdx.x;
    int m = idx >> 4, n = idx & 15;
    const float* a = c4 + m * 64;
    float acc = 0.f;
#pragma unroll
    for (int k = 0; k < 64; ++k) acc += a[k] * c5[k * 16 + n];
    S3[idx] = acc;
  }
}

// ---- chain2: Abf = bf16(S1v(256,64)@c2(64,1024)) == Amat(4096,64) flat;
//              Bbf = bf16(c3(1024,64)@S3v(64,256)) == Bmat(64,4096) flat
__global__ void chain2(const float* __restrict__ S1, const float* __restrict__ c2,
                       const float* __restrict__ c3, const float* __restrict__ S3,
                       unsigned short* __restrict__ Abf, unsigned short* __restrict__ Bbf) {
  int b = blockIdx.x;
  if (b < 1024) {
    int idx = b * 256 + threadIdx.x;
    int m = idx >> 10, n = idx & 1023;
    const float* a = S1 + m * 64;
    float acc = 0.f;
#pragma unroll
    for (int k = 0; k < 64; ++k) acc += a[k] * c2[k * 1024 + n];
    Abf[idx] = f2bf(acc);
  } else {
    int idx = (b - 1024) * 256 + threadIdx.x;
    int m = idx >> 8, n = idx & 255;
    const float* a = c3 + m * 64;
    float acc = 0.f;
#pragma unroll
    for (int k = 0; k < 64; ++k) acc += a[k] * S3[k * 256 + n];
    Bbf[idx] = f2bf(acc);
  }
}

// ---- gemm1_d4: t(8192,64) bf16 = x @ Bmat^T, barrier-free, depth-4 pipeline.
// 512 blocks x 512 thr (8 waves), 2 blocks/CU. Block owns 16 tokens; wave wv
// owns K-chunk [wv*512, +512) = 16 steps of 32. x (HBM, ~900cyc) prefetched
// 4 steps ahead in a 4-slot ring; B (L2-resident 512 KB, ~200cyc) 2 steps
// ahead in a 2-slot ring. One LDS reduction merges the 8 K-partials -> bf16 t.
__global__ __launch_bounds__(512, 4)
void gemm1_d4(const float* __restrict__ x, const unsigned short* __restrict__ Bbf,
              unsigned short* __restrict__ tb) {
  __shared__ float red[8 * 1024];  // 32 KB: per-wave 16x64 fp32 partials

  const int tid = threadIdx.x;
  const int m0 = blockIdx.x * 16;
  const int lane = tid & 63, wv = tid >> 6;
  const int r = lane & 15, q = lane >> 4;
  const float* xp = x + (size_t)(m0 + r) * DIN + wv * 512 + q * 8;
  const unsigned short* bp = Bbf + (size_t)r * DIN + wv * 512 + q * 8;

  f32x4 acc[4];
#pragma unroll
  for (int j = 0; j < 4; ++j) acc[j] = (f32x4){0.f, 0.f, 0.f, 0.f};

  // ring buffers: x depth 4 (slots = step&3), B depth 2 (slots = step&1)
  float4 xa0, xb0, xa1, xb1, xa2, xb2, xa3, xb3;
  bf16x8 b0[4], b1[4];

#define LDX(SLOT, ST)                                        \
  xa##SLOT = *(const float4*)(xp + (ST) * 32);               \
  xb##SLOT = *(const float4*)(xp + (ST) * 32 + 4);
#define LDB(BB, ST)                                          \
  _Pragma("unroll")                                          \
  for (int j = 0; j < 4; ++j)                                \
    BB[j] = *(const bf16x8*)(bp + (size_t)j * 16 * DIN + (ST) * 32);
#define MFMA4(XA, XB, BB)                                    \
  {                                                          \
    bf16x8 a;                                                \
    a[0] = (__bf16)XA.x; a[1] = (__bf16)XA.y;                \
    a[2] = (__bf16)XA.z; a[3] = (__bf16)XA.w;                \
    a[4] = (__bf16)XB.x; a[5] = (__bf16)XB.y;                \
    a[6] = (__bf16)XB.z; a[7] = (__bf16)XB.w;                \
    _Pragma("unroll")                                        \
    for (int j = 0; j < 4; ++j)                              \
      acc[j] = __builtin_amdgcn_mfma_f32_16x16x32_bf16(a, BB[j], acc[j], 0, 0, 0); \
  }

  // prologue: x steps 0..3, B steps 0..1
  LDX(0, 0) LDX(1, 1) LDX(2, 2) LDX(3, 3)
  LDB(b0, 0) LDB(b1, 1)

  // main loop: st = 0,4,8 — each sub-step consumes, then refills its slots
#pragma unroll 1
  for (int st = 0; st < 12; st += 4) {
    MFMA4(xa0, xb0, b0) LDX(0, st + 4) LDB(b0, st + 2)
    MFMA4(xa1, xb1, b1) LDX(1, st + 5) LDB(b1, st + 3)
    MFMA4(xa2, xb2, b0) LDX(2, st + 6) LDB(b0, st + 4)
    MFMA4(xa3, xb3, b1) LDX(3, st + 7) LDB(b1, st + 5)
  }
  // tail: steps 12..15 (x already resident; B needs 14,15)
  MFMA4(xa0, xb0, b0) LDB(b0, 14)
  MFMA4(xa1, xb1, b1) LDB(b1, 15)
  MFMA4(xa2, xb2, b0)
  MFMA4(xa3, xb3, b1)

#undef LDX
#undef LDB
#undef MFMA4

  // merge 8 K-partials. C/D: col = r (rank-in-tile), row = q*4+g (token)
  float* myred = red + wv * 1024;
#pragma unroll
  for (int j = 0; j < 4; ++j)
#pragma unroll
    for (int g = 0; g < 4; ++g)
      myred[(q * 4 + g) * 64 + j * 16 + r] = acc[j][g];
  __syncthreads();

  const int o = tid * 2;
  float s0 = 0.f, s1 = 0.f;
#pragma unroll
  for (int w = 0; w < 8; ++w) {
    s0 += red[w * 1024 + o];
    s1 += red[w * 1024 + o + 1];
  }
  ushort2 h = {f2bf(s0), f2bf(s1)};
  *(ushort2*)&tb[(size_t)m0 * RNK + o] = h;
}

// ---- gemm2_y: y(8192,4096) = t(8192,64) @ Amat(4096,64)^T + b ----
// (R3 version, ~write floor.) grid (16,64): 128-token x 256-col tiles, K=64
// staged once. 8 waves as 4 token-groups x 2 col-groups; 32x32x16 MFMA;
// C/D: col = lane&31, row = (reg&3)+8*(reg>>2)+4*(lane>>5) -> full-line stores.
__global__ __launch_bounds__(512)
void gemm2_y(const unsigned short* __restrict__ tbf, const unsigned short* __restrict__ Abf,
             const float* __restrict__ bias, float* __restrict__ out) {
  __shared__ __align__(16) unsigned short sm[(G2M + G2N) * AS];  // 55296 B
  unsigned short* ts = sm;             // 128 x AS
  unsigned short* as_ = sm + G2M * AS; // 256 x AS

  const int tid = threadIdx.x;
  const int m0 = blockIdx.y * G2M, n0 = blockIdx.x * G2N;
  const int lane = tid & 63, wv = tid >> 6;
  const int l31 = lane & 31, hi = lane >> 5;
  const int mw = (wv >> 1) * 32, nw = (wv & 1) * 128;

  // stage t-tile (128x64, 2 uint4/thread) and Amat-tile (256x64, 4 uint4/thread)
#pragma unroll
  for (int j = 0; j < 2; ++j) {
    int f = j * 512 + tid;
    int row = f >> 3, c = f & 7;
    *(uint4*)&ts[row * AS + c * 8] = *(const uint4*)&tbf[(size_t)(m0 + row) * RNK + c * 8];
  }
#pragma unroll
  for (int j = 0; j < 4; ++j) {
    int f = j * 512 + tid;
    int row = f >> 3, c = f & 7;
    *(uint4*)&as_[row * AS + c * 8] = *(const uint4*)&Abf[(size_t)(n0 + row) * RNK + c * 8];
  }
  __syncthreads();

  f32x16 acc[4];
#pragma unroll
  for (int j = 0; j < 4; ++j)
#pragma unroll
    for (int e = 0; e < 16; ++e) acc[j][e] = 0.f;

#pragma unroll
  for (int ks = 0; ks < 4; ++ks) {
    bf16x8 a = *(const bf16x8*)&ts[(mw + l31) * AS + ks * 16 + hi * 8];
#pragma unroll
    for (int j = 0; j < 4; ++j) {
      bf16x8 b = *(const bf16x8*)&as_[(nw + j * 32 + l31) * AS + ks * 16 + hi * 8];
      acc[j] = __builtin_amdgcn_mfma_f32_32x32x16_bf16(a, b, acc[j], 0, 0, 0);
    }
  }

  float bb[4];
#pragma unroll
  for (int j = 0; j < 4; ++j) bb[j] = bias[n0 + nw + j * 32 + l31];

#pragma unroll
  for (int j = 0; j < 4; ++j) {
    const int col = n0 + nw + j * 32 + l31;
#pragma unroll
    for (int reg = 0; reg < 16; ++reg) {
      int rowt = (reg & 3) + 8 * (reg >> 2) + 4 * hi;
      out[(size_t)(m0 + mw + rowt) * DOUT + col] = acc[j][reg] + bb[j];
    }
  }
}

extern "C" void kernel_launch(void* const* d_in, const int* in_sizes, int n_in,
                              void* d_out, int out_size, void* d_ws, size_t ws_size,
                              hipStream_t stream) {
  const float* c0 = (const float*)d_in[0];
  const float* c1 = (const float*)d_in[1];
  const float* c2 = (const float*)d_in[2];
  const float* c3 = (const float*)d_in[3];
  const float* c4 = (const float*)d_in[4];
  const float* c5 = (const float*)d_in[5];
  const float* x  = (const float*)d_in[6];
  const float* bias = (const float*)d_in[7];
  float* out = (float*)d_out;

  char* ws = (char*)d_ws;
  float*          S1  = (float*)(ws);                               // 64 KB
  float*          S3  = (float*)(ws + (1u << 16));                  // 64 KB
  unsigned short* Abf = (unsigned short*)(ws + (2u << 16));         // 512 KB
  unsigned short* Bbf = (unsigned short*)(ws + (2u << 16) + (1u << 19));  // 512 KB
  unsigned short* tbf = (unsigned short*)(ws + (2u << 16) + (2u << 19));  // 1 MB

  chain1<<<128, 256, 0, stream>>>(c0, c1, c4, c5, S1, S3);
  chain2<<<2048, 256, 0, stream>>>(S1, c2, c3, S3, Abf, Bbf);
  gemm1_d4<<<TOK / 16, 512, 0, stream>>>(x, Bbf, tbf);
  gemm2_y<<<dim3(DOUT / G2N, TOK / G2M), 512, 0, stream>>>(tbf, Abf, bias, out);
}